// Round 12
// baseline (160.164 us; speedup 1.0000x reference)
//
#include <hip/hip_runtime.h>

// 3D trilinear grid_sample (border, align_corners=False) of (4,256,256,256) f32
// voxels at N points, + bias. Output (N,4) f32.
//
// R12 = R11 (2-pass LDS-reorder radix binning, 149.5 us) with the sample
// kernel restructured for T14 issue-early/write-late staging + XCD chunking:
// 256 persistent blocks (1 per CU), each walks ~5 tiles of its XCD's
// contiguous 172-tile window (32 blocks/XCD stride-32 -> y/z halo L2 hits).
// Per tile: [convert+ds_write from regs][bar][issue next tile's 64 global
// loads into 64 VGPR][sample from LDS][bar] -> next tile's HBM latency hides
// under sampling; HBM never idles at block turnover (R6/R11's 1-block/CU
// stage/sample strict alternation). binA/binB byte-identical to R11.

#define SIDE 256
#define CHAN_STRIDE ((size_t)SIDE * SIDE * SIDE)
#define ZR 7
#define YR 7
#define NS 37                       // z-stripes
#define NTY 37                      // y-tiles per stripe
#define NTILES (NS * NTY)           // 1369
#define CNT_STRIDE 16               // ints -> 64 B per counter
#define PPT 8                       // points per thread in bin passes
#define SCAP 65536                  // stripe cap (border mean 58.6K)
#define TCAP 3072                   // tile cap (border mean ~1740)
#define BPS 32                      // pass-B blocks per stripe

// ws layout
#define SCNT_OFF 0
#define TCNT_OFF 4096
#define CNT_REGION 98304            // scnt + tcnt, zeroed each call
#define SRECS_OFF CNT_REGION
#define SRECS_BYTES ((size_t)NS * SCAP * 16)
#define TRECS_OFF (SRECS_OFF + SRECS_BYTES)
#define TRECS_BYTES ((size_t)NTILES * TCAP * 16)
#define WS_NEED (TRECS_OFF + TRECS_BYTES)   // ~106 MB

typedef float f2_unal __attribute__((ext_vector_type(2), aligned(4)));
typedef _Float16 h8_lds __attribute__((ext_vector_type(8), aligned(8)));
typedef _Float16 h8_al  __attribute__((ext_vector_type(8), aligned(16)));

// ---------------- f32 global sampling (R1, proven) -------------------------
__device__ __forceinline__ float4 sample_one(
    float px, float py, float pz,
    const float* __restrict__ vox, float4 bias)
{
    float ix = fminf(fmaxf(fmaf(px, 128.0f, 127.5f), 0.0f), 255.0f);
    float iy = fminf(fmaxf(fmaf(py, 128.0f, 127.5f), 0.0f), 255.0f);
    float iz = fminf(fmaxf(fmaf(pz, 128.0f, 127.5f), 0.0f), 255.0f);
    float fx = floorf(ix), fy = floorf(iy), fz = floorf(iz);
    float wx = ix - fx, wy = iy - fy, wz = iz - fz;
    int x0 = (int)fx, y0 = (int)fy, z0 = (int)fz;
    int xb = min(x0, SIDE - 2);
    bool xhi = (x0 > xb);
    int y1 = min(y0 + 1, SIDE - 1);
    int z1 = min(z0 + 1, SIDE - 1);
    float ux = 1.0f - wx, uy = 1.0f - wy, uz = 1.0f - wz;
    float w00 = uz * uy, w01 = uz * wy, w10 = wz * uy, w11 = wz * wy;
    size_t b00 = ((size_t)(z0 * SIDE + y0)) * SIDE + xb;
    size_t b01 = ((size_t)(z0 * SIDE + y1)) * SIDE + xb;
    size_t b10 = ((size_t)(z1 * SIDE + y0)) * SIDE + xb;
    size_t b11 = ((size_t)(z1 * SIDE + y1)) * SIDE + xb;
    float r[4];
#pragma unroll
    for (int c = 0; c < 4; ++c) {
        const float* v = vox + (size_t)c * CHAN_STRIDE;
        f2_unal q00 = *(const f2_unal*)(v + b00);
        f2_unal q01 = *(const f2_unal*)(v + b01);
        f2_unal q10 = *(const f2_unal*)(v + b10);
        f2_unal q11 = *(const f2_unal*)(v + b11);
        float a00 = xhi ? q00.y : q00.x;
        float a01 = xhi ? q01.y : q01.x;
        float a10 = xhi ? q10.y : q10.x;
        float a11 = xhi ? q11.y : q11.x;
        r[c] = w00 * fmaf(a00, ux, q00.y * wx)
             + w01 * fmaf(a01, ux, q01.y * wx)
             + w10 * fmaf(a10, ux, q10.y * wx)
             + w11 * fmaf(a11, ux, q11.y * wx);
    }
    return make_float4(r[0] + bias.x, r[1] + bias.y, r[2] + bias.z, r[3] + bias.w);
}

// ---------------- pass A: bin by z-stripe, LDS reorder, coalesced write ----
__global__ __launch_bounds__(256) void binA_kernel(
    const float* __restrict__ pos, int n,
    int* __restrict__ scnt, uint4* __restrict__ srecs,
    const float* __restrict__ vox, const float* __restrict__ biasp,
    float4* __restrict__ out)
{
    __shared__ int hist[NS], pref[NS + 1], gbase[NS];
    __shared__ uint4 sbuf[256 * PPT];
    __shared__ short sbin[256 * PPT];
    int tid = threadIdx.x;
    if (tid < NS) hist[tid] = 0;
    __syncthreads();

    size_t start = ((size_t)blockIdx.x * 256 + tid) * PPT;
    float buf[3 * PPT];
    bool full = (start + PPT <= (size_t)n);
    if (full) {
        const float4* p4 = (const float4*)(pos + 3 * start);
#pragma unroll
        for (int k = 0; k < 3 * PPT / 4; ++k) ((float4*)buf)[k] = p4[k];
    } else {
#pragma unroll
        for (int k = 0; k < 3 * PPT; ++k) {
            size_t e = 3 * start + k;
            buf[k] = (e < 3 * (size_t)n) ? pos[e] : 0.0f;
        }
    }

    int bin[PPT], rank[PPT];
#pragma unroll
    for (int j = 0; j < PPT; ++j) {
        bin[j] = -1;
        if (start + j < (size_t)n) {
            float pz = buf[3 * j + 2];
            float izf = fminf(fmaxf(fmaf(pz, 128.0f, 127.5f), 0.0f), 255.0f);
            int zs = ((int)floorf(izf)) / ZR;
            bin[j] = zs;
            rank[j] = atomicAdd(&hist[zs], 1);
        }
    }
    __syncthreads();
    if (tid == 0) {
        int s = 0;
#pragma unroll
        for (int b = 0; b < NS; ++b) { pref[b] = s; s += hist[b]; }
        pref[NS] = s;
    }
    __syncthreads();
#pragma unroll
    for (int j = 0; j < PPT; ++j) {
        if (bin[j] < 0) continue;
        int slot = pref[bin[j]] + rank[j];
        uint4 r;
        r.x = __float_as_uint(buf[3 * j + 0]);
        r.y = __float_as_uint(buf[3 * j + 1]);
        r.z = __float_as_uint(buf[3 * j + 2]);
        r.w = (unsigned)(start + j);
        sbuf[slot] = r;
        sbin[slot] = (short)bin[j];
    }
    if (tid < NS) gbase[tid] = hist[tid] ? atomicAdd(&scnt[tid * CNT_STRIDE], hist[tid]) : 0;
    __syncthreads();

    int tot = pref[NS];
    float4 bias = *(const float4*)biasp;
    for (int k = tid; k < tot; k += 256) {
        int b = sbin[k];
        int dst = gbase[b] + (k - pref[b]);
        uint4 r = sbuf[k];
        if (dst < SCAP) {
            srecs[(size_t)b * SCAP + dst] = r;   // coalesced ~880B runs
        } else {
            out[r.w] = sample_one(__uint_as_float(r.x), __uint_as_float(r.y),
                                  __uint_as_float(r.z), vox, bias);
        }
    }
}

// ---------------- pass B: per stripe, bin by y-tile, coalesced write -------
__global__ __launch_bounds__(256) void binB_kernel(
    const int* __restrict__ scnt, const uint4* __restrict__ srecs,
    int* __restrict__ tcnt, uint4* __restrict__ trecs,
    const float* __restrict__ vox, const float* __restrict__ biasp,
    float4* __restrict__ out)
{
    __shared__ int hist[NTY], pref[NTY + 1], gbase[NTY];
    __shared__ uint4 sbuf[256 * PPT];
    __shared__ short sbin[256 * PPT];
    int tid = threadIdx.x;
    int s = blockIdx.x / BPS, blk = blockIdx.x % BPS;
    int cnt = min(scnt[s * CNT_STRIDE], SCAP);
    int base = blk * 256 * PPT;
    if (tid < NTY) hist[tid] = 0;
    __syncthreads();

    uint4 R[PPT];
    int bin[PPT], rank[PPT];
#pragma unroll
    for (int j = 0; j < PPT; ++j) {
        bin[j] = -1;
        int ridx = base + j * 256 + tid;         // coalesced 1KB/wave
        if (ridx < cnt) {
            R[j] = srecs[(size_t)s * SCAP + ridx];
            float py = __uint_as_float(R[j].y);
            float iyf = fminf(fmaxf(fmaf(py, 128.0f, 127.5f), 0.0f), 255.0f);
            int yt = ((int)floorf(iyf)) / YR;
            bin[j] = yt;
            rank[j] = atomicAdd(&hist[yt], 1);
        }
    }
    __syncthreads();
    if (tid == 0) {
        int t = 0;
#pragma unroll
        for (int b = 0; b < NTY; ++b) { pref[b] = t; t += hist[b]; }
        pref[NTY] = t;
    }
    __syncthreads();
#pragma unroll
    for (int j = 0; j < PPT; ++j) {
        if (bin[j] < 0) continue;
        int slot = pref[bin[j]] + rank[j];
        sbuf[slot] = R[j];
        sbin[slot] = (short)bin[j];
    }
    if (tid < NTY)
        gbase[tid] = hist[tid]
            ? atomicAdd(&tcnt[(s * NTY + tid) * CNT_STRIDE], hist[tid]) : 0;
    __syncthreads();

    int tot = pref[NTY];
    float4 bias = *(const float4*)biasp;
    for (int k = tid; k < tot; k += 256) {
        int b = sbin[k];
        int dst = gbase[b] + (k - pref[b]);
        uint4 r = sbuf[k];
        if (dst < TCAP) {
            trecs[(size_t)(s * NTY + b) * TCAP + dst] = r;
        } else {
            out[r.w] = sample_one(__uint_as_float(r.x), __uint_as_float(r.y),
                                  __uint_as_float(r.z), vox, bias);
        }
    }
}

// ---------------- sample pass: persistent, T14 prefetch, XCD chunks --------
#define SGRID 256
#define CPX ((NTILES + 7) / 8)      // 172 tiles per XCD chunk

__global__ __launch_bounds__(1024) void sample_tiles_kernel(
    const uint4* __restrict__ trecs, const int* __restrict__ tcnt,
    const float* __restrict__ vox, const float* __restrict__ biasp,
    float4* __restrict__ out)
{
    __shared__ _Float16 tile[8 * 8 * 256 * 4];  // 128 KiB

    float4 bias = *(const float4*)biasp;
    int tid = threadIdx.x;
    int xcd = blockIdx.x & 7;          // dispatch round-robin heuristic
    int ib  = blockIdx.x >> 3;         // 0..31 within XCD

    // this thread's fixed (chunk-local) coords
    int p_   = tid & 127;              // x-pair index
    int rowp = tid >> 7;               // chunk base row (stride 8 per it)
    // per-tile loads live here across phases: [ch][it]
    float2 L[4][8];

    // tile for step k of this block (contiguous CPX-window per XCD)
    auto tile_of = [&](int k) -> int {
        int local = ib + k * 32;
        if (local >= CPX) return -1;
        int t = xcd * CPX + local;
        return (t < NTILES) ? t : -1;
    };

    int t = tile_of(0);
    if (t < 0) return;

    // ---- issue loads for tile t (no wait) ----
    auto issue = [&](int tt) {
        int zt = tt / NTY, yt = tt - zt * NTY;
        int zbase = zt * ZR, ybase = yt * YR;
#pragma unroll
        for (int it = 0; it < 8; ++it) {
            int row = rowp + it * 8;           // 0..63
            int r = row & 7, pl = row >> 3;
            int zp = min(zbase + pl, SIDE - 1);
            int yp = min(ybase + r, SIDE - 1);
            size_t g = ((size_t)(zp * SIDE + yp)) * SIDE + p_ * 2;
            L[0][it] = *(const float2*)(vox + g);
            L[1][it] = *(const float2*)(vox + CHAN_STRIDE + g);
            L[2][it] = *(const float2*)(vox + 2 * CHAN_STRIDE + g);
            L[3][it] = *(const float2*)(vox + 3 * CHAN_STRIDE + g);
        }
    };

    // ---- convert L -> fp16 LDS tile (first use of L => waits here) ----
    auto write_tile = [&]() {
#pragma unroll
        for (int it = 0; it < 8; ++it) {
            int row = rowp + it * 8;
            h8_al o;
            o[0] = (_Float16)L[0][it].x; o[1] = (_Float16)L[1][it].x;
            o[2] = (_Float16)L[2][it].x; o[3] = (_Float16)L[3][it].x;
            o[4] = (_Float16)L[0][it].y; o[5] = (_Float16)L[1][it].y;
            o[6] = (_Float16)L[2][it].y; o[7] = (_Float16)L[3][it].y;
            *(h8_al*)(tile + ((size_t)row * 256 + p_ * 2) * 4) = o;
        }
    };

    issue(t);
    int k = 0;
    while (true) {
        write_tile();
        __syncthreads();                 // tile ready for everyone

        int tn = tile_of(k + 1);
        if (tn >= 0) issue(tn);          // flies during sampling

        // ---- sample tile t from LDS ----
        int zt = t / NTY, yt = t - zt * NTY;
        int zbase = zt * ZR, ybase = yt * YR;
        int cnt = min(tcnt[t * CNT_STRIDE], TCAP);
        const uint4* rec = trecs + (size_t)t * TCAP;
        for (int r = tid; r < cnt; r += 1024) {
            uint4 R = rec[r];
            float px = __uint_as_float(R.x);
            float py = __uint_as_float(R.y);
            float pz = __uint_as_float(R.z);

            float ix = fminf(fmaxf(fmaf(px, 128.0f, 127.5f), 0.0f), 255.0f);
            float iy = fminf(fmaxf(fmaf(py, 128.0f, 127.5f), 0.0f), 255.0f);
            float iz = fminf(fmaxf(fmaf(pz, 128.0f, 127.5f), 0.0f), 255.0f);
            float fx = floorf(ix), fy = floorf(iy), fz = floorf(iz);
            float wx = ix - fx, wy = iy - fy, wz = iz - fz;
            int x0 = (int)fx, y0 = (int)fy, z0 = (int)fz;
            int xb = min(x0, SIDE - 2);
            bool xhi = (x0 > xb);
            int y1 = min(y0 + 1, SIDE - 1);
            int z1 = min(z0 + 1, SIDE - 1);

            int zl = z0 - zbase, zl1 = z1 - zbase;
            int yl = y0 - ybase, yl1 = y1 - ybase;

            float ux = 1.0f - wx, uy = 1.0f - wy, uz = 1.0f - wz;
            float w00 = uz * uy, w01 = uz * wy, w10 = wz * uy, w11 = wz * wy;

            h8_lds v00 = *(const h8_lds*)(tile + ((zl  * 8 + yl ) * 256 + xb) * 4);
            h8_lds v01 = *(const h8_lds*)(tile + ((zl  * 8 + yl1) * 256 + xb) * 4);
            h8_lds v10 = *(const h8_lds*)(tile + ((zl1 * 8 + yl ) * 256 + xb) * 4);
            h8_lds v11 = *(const h8_lds*)(tile + ((zl1 * 8 + yl1) * 256 + xb) * 4);

            float acc[4];
#pragma unroll
            for (int c = 0; c < 4; ++c) {
                float lo00 = (float)(xhi ? v00[4 + c] : v00[c]);
                float lo01 = (float)(xhi ? v01[4 + c] : v01[c]);
                float lo10 = (float)(xhi ? v10[4 + c] : v10[c]);
                float lo11 = (float)(xhi ? v11[4 + c] : v11[c]);
                float hi00 = (float)v00[4 + c];
                float hi01 = (float)v01[4 + c];
                float hi10 = (float)v10[4 + c];
                float hi11 = (float)v11[4 + c];
                acc[c] = w00 * fmaf(lo00, ux, hi00 * wx)
                       + w01 * fmaf(lo01, ux, hi01 * wx)
                       + w10 * fmaf(lo10, ux, hi10 * wx)
                       + w11 * fmaf(lo11, ux, hi11 * wx);
            }
            out[R.w] = make_float4(acc[0] + bias.x, acc[1] + bias.y,
                                   acc[2] + bias.z, acc[3] + bias.w);
        }

        if (tn < 0) break;
        __syncthreads();                 // everyone done reading tile
        t = tn; ++k;
    }
}

// ---------------- fallback: direct (R1, 636 us) ----------------------------
__global__ __launch_bounds__(256) void vox_trilerp_kernel(
    const float* __restrict__ pos, const float* __restrict__ vox,
    const float* __restrict__ biasp, float* __restrict__ out, int n)
{
    int i = blockIdx.x * blockDim.x + threadIdx.x;
    if (i >= n) return;
    float4 bias = *(const float4*)biasp;
    float4 res = sample_one(pos[3 * (size_t)i], pos[3 * (size_t)i + 1],
                            pos[3 * (size_t)i + 2], vox, bias);
    *(float4*)(out + 4 * (size_t)i) = res;
}

extern "C" void kernel_launch(void* const* d_in, const int* in_sizes, int n_in,
                              void* d_out, int out_size, void* d_ws, size_t ws_size,
                              hipStream_t stream) {
    const float* pos  = (const float*)d_in[0];
    const float* vox  = (const float*)d_in[1];
    const float* bias = (const float*)d_in[2];
    float* out = (float*)d_out;

    int n = in_sizes[0] / 3;

    if (ws_size >= WS_NEED && n >= 256 * PPT) {
        int* scnt    = (int*)((char*)d_ws + SCNT_OFF);
        int* tcnt    = (int*)((char*)d_ws + TCNT_OFF);
        uint4* srecs = (uint4*)((char*)d_ws + SRECS_OFF);
        uint4* trecs = (uint4*)((char*)d_ws + TRECS_OFF);
        hipMemsetAsync(d_ws, 0, CNT_REGION, stream);
        int grid1 = (n + 256 * PPT - 1) / (256 * PPT);
        binA_kernel<<<grid1, 256, 0, stream>>>(pos, n, scnt, srecs, vox, bias,
                                               (float4*)out);
        binB_kernel<<<NS * BPS, 256, 0, stream>>>(scnt, srecs, tcnt, trecs,
                                                  vox, bias, (float4*)out);
        sample_tiles_kernel<<<SGRID, 1024, 0, stream>>>(trecs, tcnt, vox, bias,
                                                        (float4*)out);
    } else {
        int grid = (n + 255) / 256;
        vox_trilerp_kernel<<<grid, 256, 0, stream>>>(pos, vox, bias, out, n);
    }
}